// Round 1
// baseline (2766.845 us; speedup 1.0000x reference)
//
#include <hip/hip_runtime.h>
#include <hip/hip_bf16.h>
#include <math.h>

// Problem constants
#define BB 16
#define SS 512
#define DIM 768
#define HH 12
#define HD 64
#define II 3072
#define NROWS (BB*SS)          // 8192
#define QKV_N (3*DIM)          // 2304

// ---------------------------------------------------------------------------
// Generic fp32 NT GEMM: C[m,n] = sum_k A[m,k] * B[n,k]  (+bias, +resid)
// MODE 0: C = A B^T + bias (+ resid)
// MODE 1: C = gelu(A B1^T) * (A B2^T)      (GLU fused gating)
// BK=32. 256 threads. Tiles stored transposed in LDS with +4 pad.
// All dims assumed divisible by tile sizes (true for this problem).
// ---------------------------------------------------------------------------

template<int ROWS>
__device__ __forceinline__ void stage_tile(const float* __restrict__ g, int ld,
                                           float* __restrict__ s, int tid)
{
    // loads ROWS x 32 tile (row-major, row stride ld) -> s[k][r], pitch ROWS+4
    constexpr int PER = (ROWS * 8) / 256;   // float4s per thread
    constexpr int PITCH = ROWS + 4;
#pragma unroll
    for (int i = 0; i < PER; ++i) {
        int f  = tid + i * 256;
        int r  = f >> 3;          // row within tile
        int c4 = f & 7;           // float4 index along k
        float4 v = *(const float4*)(g + (size_t)r * ld + c4 * 4);
        int kk = c4 * 4;
        s[(kk + 0) * PITCH + r] = v.x;
        s[(kk + 1) * PITCH + r] = v.y;
        s[(kk + 2) * PITCH + r] = v.z;
        s[(kk + 3) * PITCH + r] = v.w;
    }
}

__device__ __forceinline__ float gelu_exact(float x)
{
    return 0.5f * x * (1.0f + erff(x * 0.70710678118654752f));
}

template<int MODE, int BM, int BN, int TM, int TN>
__global__ __launch_bounds__(256) void gemm_nt(
    const float* __restrict__ A, const float* __restrict__ Bm,
    const float* __restrict__ B2, const float* __restrict__ bias,
    const float* __restrict__ resid, float* __restrict__ C,
    int M, int N, int K)
{
    constexpr int BK = 32;
    constexpr int PA = BM + 4, PB = BN + 4;
    static_assert((BM / TM) * (BN / TN) == 256, "thread grid");

    extern __shared__ float sm[];
    float* As  = sm;
    float* Bs  = As + BK * PA;
    float* Bs2 = Bs + BK * PB;      // only used when MODE==1

    const int tid = threadIdx.x;
    const int tx  = tid % (BN / TN);
    const int ty  = tid / (BN / TN);
    const int row0 = blockIdx.y * BM;
    const int col0 = blockIdx.x * BN;

    const float* Ag  = A  + (size_t)row0 * K;
    const float* Bg  = Bm + (size_t)col0 * K;
    const float* B2g = MODE ? (B2 + (size_t)col0 * K) : nullptr;

    float acc[TM][TN] = {};
    float acc2[MODE ? TM : 1][MODE ? TN : 1] = {};

    for (int k0 = 0; k0 < K; k0 += BK) {
        __syncthreads();
        stage_tile<BM>(Ag + k0, K, As, tid);
        stage_tile<BN>(Bg + k0, K, Bs, tid);
        if (MODE) stage_tile<BN>(B2g + k0, K, Bs2, tid);
        __syncthreads();

#pragma unroll
        for (int kk = 0; kk < BK; ++kk) {
            float a[TM], b[TN], b2[MODE ? TN : 1];
#pragma unroll
            for (int i = 0; i < TM / 4; ++i) {
                float4 t = *(const float4*)&As[kk * PA + ty * TM + i * 4];
                a[i*4+0] = t.x; a[i*4+1] = t.y; a[i*4+2] = t.z; a[i*4+3] = t.w;
            }
#pragma unroll
            for (int j = 0; j < TN / 4; ++j) {
                float4 t = *(const float4*)&Bs[kk * PB + tx * TN + j * 4];
                b[j*4+0] = t.x; b[j*4+1] = t.y; b[j*4+2] = t.z; b[j*4+3] = t.w;
            }
            if (MODE) {
#pragma unroll
                for (int j = 0; j < TN / 4; ++j) {
                    float4 t = *(const float4*)&Bs2[kk * PB + tx * TN + j * 4];
                    b2[j*4+0] = t.x; b2[j*4+1] = t.y; b2[j*4+2] = t.z; b2[j*4+3] = t.w;
                }
            }
#pragma unroll
            for (int i = 0; i < TM; ++i)
#pragma unroll
                for (int j = 0; j < TN; ++j) {
                    acc[i][j] = fmaf(a[i], b[j], acc[i][j]);
                    if (MODE) acc2[i][j] = fmaf(a[i], b2[j], acc2[i][j]);
                }
        }
    }

    // epilogue
#pragma unroll
    for (int i = 0; i < TM; ++i) {
        const size_t m = row0 + ty * TM + i;
        const int    nbase = col0 + tx * TN;
        float* crow = C + m * N + nbase;
#pragma unroll
        for (int j4 = 0; j4 < TN / 4; ++j4) {
            float4 w;
            if (MODE == 0) {
                w.x = acc[i][j4*4+0] + bias[nbase + j4*4+0];
                w.y = acc[i][j4*4+1] + bias[nbase + j4*4+1];
                w.z = acc[i][j4*4+2] + bias[nbase + j4*4+2];
                w.w = acc[i][j4*4+3] + bias[nbase + j4*4+3];
                if (resid) {
                    const float4 r = *(const float4*)(resid + m * N + nbase + j4*4);
                    w.x += r.x; w.y += r.y; w.z += r.z; w.w += r.w;
                }
            } else {
                w.x = gelu_exact(acc[i][j4*4+0]) * acc2[i][j4*4+0];
                w.y = gelu_exact(acc[i][j4*4+1]) * acc2[i][j4*4+1];
                w.z = gelu_exact(acc[i][j4*4+2]) * acc2[i][j4*4+2];
                w.w = gelu_exact(acc[i][j4*4+3]) * acc2[i][j4*4+3];
            }
            *(float4*)(crow + j4 * 4) = w;
        }
    }
}

// ---------------------------------------------------------------------------
// Flash-style attention. One block = one (b, h, 64-query tile).
// qkv layout: [B*S, 3*DIM] row-major; q at col h*64, k at 768+h*64, v at 1536+h*64.
// ALiBi bias computed from slopes (the 201MB bias tensor is never read).
// ctx written row-major [B*S, DIM] with col h*64+d.
// ---------------------------------------------------------------------------
__global__ __launch_bounds__(256) void attn_kernel(
    const float* __restrict__ qkv, const float* __restrict__ slopes,
    float* __restrict__ ctx)
{
    __shared__ float Ks[64][68];
    __shared__ float Vs[64][68];
    __shared__ float Ps[64][68];

    const int q0 = blockIdx.x * 64;
    const int h  = blockIdx.y;
    const int b  = blockIdx.z;
    const int tid = threadIdx.x;
    const int qr = tid >> 2;        // query row within tile (0..63)
    const int qc = tid & 3;         // quarter (0..3): owns cols/dims qc*16..qc*16+15
    const float slope = slopes[h];
    const float scale = 0.125f;     // 1/sqrt(64)

    // load my query row into registers (4 threads per row duplicate; L2-cached)
    float q[HD];
    {
        const float* qrow = qkv + ((size_t)(b * SS + q0 + qr)) * QKV_N + h * HD;
#pragma unroll
        for (int i = 0; i < HD / 4; ++i) {
            float4 t = *(const float4*)&qrow[i * 4];
            q[i*4+0] = t.x; q[i*4+1] = t.y; q[i*4+2] = t.z; q[i*4+3] = t.w;
        }
    }

    float mrun = -1e30f, lrun = 0.f;
    float o[16] = {};

    for (int kt = 0; kt < SS; kt += 64) {
        __syncthreads();   // previous PV/read of Ks/Vs/Ps done
        {
            const float* kbase = qkv + ((size_t)(b * SS + kt + qr)) * QKV_N + DIM + h * HD;
            const float* vbase = kbase + DIM;
#pragma unroll
            for (int i = 0; i < 4; ++i) {
                *(float4*)&Ks[qr][qc * 16 + i * 4] = *(const float4*)&kbase[qc * 16 + i * 4];
                *(float4*)&Vs[qr][qc * 16 + i * 4] = *(const float4*)&vbase[qc * 16 + i * 4];
            }
        }
        __syncthreads();

        // scores for my 16 key columns: c = qc*16 + j
        float p[16];
        float tmax = -1e30f;
#pragma unroll
        for (int j = 0; j < 16; ++j) {
            const int c = qc * 16 + j;
            float s = 0.f;
#pragma unroll
            for (int d4 = 0; d4 < 16; ++d4) {
                float4 kv = *(const float4*)&Ks[c][d4 * 4];
                s = fmaf(q[d4*4+0], kv.x, s);
                s = fmaf(q[d4*4+1], kv.y, s);
                s = fmaf(q[d4*4+2], kv.z, s);
                s = fmaf(q[d4*4+3], kv.w, s);
            }
            int dist = (q0 + qr) - (kt + c);
            s = s * scale - slope * fabsf((float)dist);
            p[j] = s;
            tmax = fmaxf(tmax, s);
        }
        // reduce max over the 4 threads of this row (consecutive lanes)
        tmax = fmaxf(tmax, __shfl_xor(tmax, 1));
        tmax = fmaxf(tmax, __shfl_xor(tmax, 2));
        const float mnew = fmaxf(mrun, tmax);
        const float corr = __expf(mrun - mnew);
        float lsum = 0.f;
#pragma unroll
        for (int j = 0; j < 16; ++j) {
            p[j] = __expf(p[j] - mnew);
            lsum += p[j];
        }
        lsum += __shfl_xor(lsum, 1);
        lsum += __shfl_xor(lsum, 2);
        lrun = lrun * corr + lsum;
        mrun = mnew;
#pragma unroll
        for (int j = 0; j < 16; ++j) o[j] *= corr;

        // publish P tile
#pragma unroll
        for (int j4 = 0; j4 < 4; ++j4) {
            float4 w; w.x = p[j4*4+0]; w.y = p[j4*4+1]; w.z = p[j4*4+2]; w.w = p[j4*4+3];
            *(float4*)&Ps[qr][qc * 16 + j4 * 4] = w;
        }
        __syncthreads();

        // PV: my output dims d = qc*16 .. qc*16+15
#pragma unroll 8
        for (int c = 0; c < 64; ++c) {
            const float pc = Ps[qr][c];
#pragma unroll
            for (int j4 = 0; j4 < 4; ++j4) {
                float4 v = *(const float4*)&Vs[c][qc * 16 + j4 * 4];
                o[j4*4+0] = fmaf(pc, v.x, o[j4*4+0]);
                o[j4*4+1] = fmaf(pc, v.y, o[j4*4+1]);
                o[j4*4+2] = fmaf(pc, v.z, o[j4*4+2]);
                o[j4*4+3] = fmaf(pc, v.w, o[j4*4+3]);
            }
        }
    }

    const float inv = 1.0f / lrun;
    float* crow = ctx + ((size_t)(b * SS + q0 + qr)) * DIM + h * HD + qc * 16;
#pragma unroll
    for (int j4 = 0; j4 < 4; ++j4) {
        float4 w;
        w.x = o[j4*4+0] * inv; w.y = o[j4*4+1] * inv;
        w.z = o[j4*4+2] * inv; w.w = o[j4*4+3] * inv;
        *(float4*)&crow[j4 * 4] = w;
    }
}

// ---------------------------------------------------------------------------
// LayerNorm over last dim (768). One block per row, 256 threads x 3 elems.
// ---------------------------------------------------------------------------
__global__ __launch_bounds__(256) void ln_kernel(
    const float* __restrict__ x, const float* __restrict__ gw,
    const float* __restrict__ bw, float* __restrict__ y)
{
    const int row = blockIdx.x;
    const int tid = threadIdx.x;
    const float* xr = x + (size_t)row * DIM;
    float v0 = xr[tid], v1 = xr[tid + 256], v2 = xr[tid + 512];
    float s  = v0 + v1 + v2;
    float ss = v0 * v0 + v1 * v1 + v2 * v2;
#pragma unroll
    for (int off = 1; off < 64; off <<= 1) {
        s  += __shfl_xor(s,  off);
        ss += __shfl_xor(ss, off);
    }
    __shared__ float rs[4], rss[4];
    const int wid = tid >> 6;
    if ((tid & 63) == 0) { rs[wid] = s; rss[wid] = ss; }
    __syncthreads();
    s  = rs[0] + rs[1] + rs[2] + rs[3];
    ss = rss[0] + rss[1] + rss[2] + rss[3];
    const float mean = s * (1.0f / DIM);
    float var = ss * (1.0f / DIM) - mean * mean;
    var = fmaxf(var, 0.0f);
    const float r = rsqrtf(var + 1e-12f);
    float* yr = y + (size_t)row * DIM;
    yr[tid]       = (v0 - mean) * r * gw[tid]       + bw[tid];
    yr[tid + 256] = (v1 - mean) * r * gw[tid + 256] + bw[tid + 256];
    yr[tid + 512] = (v2 - mean) * r * gw[tid + 512] + bw[tid + 512];
}

// ---------------------------------------------------------------------------
extern "C" void kernel_launch(void* const* d_in, const int* in_sizes, int n_in,
                              void* d_out, int out_size, void* d_ws, size_t ws_size,
                              hipStream_t stream)
{
    const float* x      = (const float*)d_in[0];   // hidden_states (8192,768)
    // d_in[1] cu_seqlens, d_in[2] seqlen, d_in[3] bias: unused (recomputed)
    const float* slopes = (const float*)d_in[4];
    const float* Wqkv   = (const float*)d_in[5];
    const float* bqkv   = (const float*)d_in[6];
    const float* Wo     = (const float*)d_in[7];
    const float* bo     = (const float*)d_in[8];
    const float* ln1g   = (const float*)d_in[9];
    const float* ln1b   = (const float*)d_in[10];
    const float* Wglu   = (const float*)d_in[11];
    const float* Wdown  = (const float*)d_in[12];
    const float* bdown  = (const float*)d_in[13];
    const float* ln2g   = (const float*)d_in[14];
    const float* ln2b   = (const float*)d_in[15];
    float* out = (float*)d_out;
    float* ws  = (float*)d_ws;

    // workspace layout (floats):
    //   [0, 8192*2304)                      qkv        (dead after attn)
    //   [8192*2304, 8192*3072)              ctx        (dead after wo gemm)
    //   [0, 8192*3072)                      gated      (aliases qkv+ctx, used later)
    //   [8192*3072, 8192*3840)              attn_out
    //   [8192*3840, 8192*4608)              tmp (ln inputs, reused twice)
    float* qkv      = ws;
    float* ctx      = ws + (size_t)NROWS * QKV_N;
    float* gated    = ws;
    float* attn_out = ws + (size_t)NROWS * 3072;
    float* tmp      = attn_out + (size_t)NROWS * DIM;

    constexpr int BK = 32;
    const size_t sh0 = (size_t)BK * (128 + 4) * 2 * sizeof(float);                 // mode0
    const size_t sh1 = (size_t)BK * ((64 + 4) + 2 * (128 + 4)) * sizeof(float);    // mode1

    // 1) qkv = x @ Wqkv^T + bqkv
    gemm_nt<0,128,128,8,8><<<dim3(QKV_N/128, NROWS/128), 256, sh0, stream>>>(
        x, Wqkv, nullptr, bqkv, nullptr, qkv, NROWS, QKV_N, DIM);

    // 2) attention -> ctx
    attn_kernel<<<dim3(SS/64, HH, BB), 256, 0, stream>>>(qkv, slopes, ctx);

    // 3) tmp = ctx @ Wo^T + bo + x
    gemm_nt<0,128,128,8,8><<<dim3(DIM/128, NROWS/128), 256, sh0, stream>>>(
        ctx, Wo, nullptr, bo, x, tmp, NROWS, DIM, DIM);

    // 4) attn_out = LN1(tmp)
    ln_kernel<<<NROWS, 256, 0, stream>>>(tmp, ln1g, ln1b, attn_out);

    // 5) gated = gelu(attn_out @ Wglu[:I]^T) * (attn_out @ Wglu[I:]^T)
    gemm_nt<1,64,128,4,8><<<dim3(II/128, NROWS/64), 256, sh1, stream>>>(
        attn_out, Wglu, Wglu + (size_t)II * DIM, nullptr, nullptr, gated,
        NROWS, II, DIM);

    // 6) tmp = gated @ Wdown^T + bdown + attn_out
    gemm_nt<0,128,128,8,8><<<dim3(DIM/128, NROWS/128), 256, sh0, stream>>>(
        gated, Wdown, nullptr, bdown, attn_out, tmp, NROWS, DIM, II);

    // 7) out = LN2(tmp)
    ln_kernel<<<NROWS, 256, 0, stream>>>(tmp, ln2g, ln2b, out);
}

// Round 3
// 1106.125 us; speedup vs baseline: 2.5014x; 2.5014x over previous
//
#include <hip/hip_runtime.h>
#include <hip/hip_bf16.h>
#include <math.h>

// Problem constants
#define BB 16
#define SS 512
#define DIM 768
#define HH 12
#define HD 64
#define II 3072
#define NROWS (BB*SS)          // 8192
#define QKV_N (3*DIM)          // 2304

typedef __attribute__((ext_vector_type(8))) short bf16x8;
typedef __attribute__((ext_vector_type(4))) float f32x4;

__device__ __forceinline__ unsigned short f2b(float f) {
    __hip_bfloat16 h = __float2bfloat16(f);   // RNE
    return *reinterpret_cast<unsigned short*>(&h);
}

__device__ __forceinline__ void gload_lds16(const void* g, void* l) {
    // wave-uniform LDS base; HW scatters lane*16
    __builtin_amdgcn_global_load_lds(
        (const __attribute__((address_space(1))) void*)g,
        (__attribute__((address_space(3))) void*)l, 16, 0, 0);
}

__device__ __forceinline__ float gelu_exact(float x) {
    return 0.5f * x * (1.0f + erff(x * 0.70710678118654752f));
}

// ---------------------------------------------------------------------------
// fp32 -> bf16 conversion (vectorized, grid-stride). n4 = n/4.
// ---------------------------------------------------------------------------
__global__ __launch_bounds__(256) void cvt_bf16_kernel(
    const float* __restrict__ src, unsigned short* __restrict__ dst, int n4)
{
    const int stride = gridDim.x * 256;
    for (int i = blockIdx.x * 256 + threadIdx.x; i < n4; i += stride) {
        float4 v = ((const float4*)src)[i];
        ushort4 o;
        o.x = f2b(v.x); o.y = f2b(v.y); o.z = f2b(v.z); o.w = f2b(v.w);
        ((ushort4*)dst)[i] = o;
    }
}

// ---------------------------------------------------------------------------
// bf16 MFMA GEMM, NT: C[m,n] = sum_k A[m,k]*B[n,k] + bias[n] (+resid[m,n])
// A,B bf16 row-major (ld = K). C fp32. 128x128 tile, BK=32, 4 waves (2x2).
// resid may alias C (per-element read-then-write by the same thread).
// ---------------------------------------------------------------------------
__global__ __launch_bounds__(256) void gemm_bf16_f32(
    const unsigned short* __restrict__ A, const unsigned short* __restrict__ B,
    const float* __restrict__ bias, const float* __restrict__ resid,
    float* __restrict__ C, int M, int N, int K)
{
    __shared__ unsigned short Alds[128 * 32];
    __shared__ unsigned short Blds[128 * 32];

    const int tid  = threadIdx.x;
    const int wave = tid >> 6, lane = tid & 63;
    const int wr = wave >> 1, wc = wave & 1;
    const int l15 = lane & 15, l4 = lane >> 4;
    const int row0 = blockIdx.y * 128, col0 = blockIdx.x * 128;

    f32x4 acc[4][4];
#pragma unroll
    for (int i = 0; i < 4; ++i)
#pragma unroll
        for (int j = 0; j < 4; ++j) acc[i][j] = (f32x4)0.0f;

    int aoff[4], boff[4];
#pragma unroll
    for (int mi = 0; mi < 4; ++mi) aoff[mi] = ((wr * 64 + mi * 16 + l15) * 32 + l4 * 8) * 2;
#pragma unroll
    for (int ni = 0; ni < 4; ++ni) boff[ni] = ((wc * 64 + ni * 16 + l15) * 32 + l4 * 8) * 2;

    for (int k0 = 0; k0 < K; k0 += 32) {
        __syncthreads();
#pragma unroll
        for (int i = 0; i < 2; ++i) {
            const int base = i * 256 + wave * 64;   // wave-uniform
            const int idx  = base + lane;
            const int r = idx >> 2, sg = idx & 3;
            gload_lds16(A + (size_t)(row0 + r) * K + k0 + sg * 8, (char*)Alds + base * 16);
            gload_lds16(B + (size_t)(col0 + r) * K + k0 + sg * 8, (char*)Blds + base * 16);
        }
        __syncthreads();

        bf16x8 af[4], bfr[4];
#pragma unroll
        for (int mi = 0; mi < 4; ++mi) af[mi]  = *(const bf16x8*)((const char*)Alds + aoff[mi]);
#pragma unroll
        for (int ni = 0; ni < 4; ++ni) bfr[ni] = *(const bf16x8*)((const char*)Blds + boff[ni]);
#pragma unroll
        for (int mi = 0; mi < 4; ++mi)
#pragma unroll
            for (int ni = 0; ni < 4; ++ni)
                acc[mi][ni] = __builtin_amdgcn_mfma_f32_16x16x32_bf16(
                    af[mi], bfr[ni], acc[mi][ni], 0, 0, 0);
    }

    float bv[4];
#pragma unroll
    for (int ni = 0; ni < 4; ++ni) bv[ni] = bias[col0 + wc * 64 + ni * 16 + l15];

#pragma unroll
    for (int mi = 0; mi < 4; ++mi) {
        const int rowb = row0 + wr * 64 + mi * 16 + l4 * 4;
#pragma unroll
        for (int ni = 0; ni < 4; ++ni) {
            const int col = col0 + wc * 64 + ni * 16 + l15;
#pragma unroll
            for (int r = 0; r < 4; ++r) {
                float v = acc[mi][ni][r] + bv[ni];
                const size_t off = (size_t)(rowb + r) * N + col;
                if (resid) v += resid[off];
                C[off] = v;
            }
        }
    }
}

// ---------------------------------------------------------------------------
// GLU GEMM: gated[m,n] = gelu(A @ Bg[n]^T) * (A @ Bu[n]^T), bf16 out.
// 64x128 tile (M x N-per-half), BK=32, 4 waves (2x2), dual B accumulators.
// ---------------------------------------------------------------------------
__global__ __launch_bounds__(256) void gemm_bf16_glu(
    const unsigned short* __restrict__ A, const unsigned short* __restrict__ Bg,
    const unsigned short* __restrict__ Bu, unsigned short* __restrict__ Cbf,
    int M, int N, int K)
{
    __shared__ unsigned short Alds[64 * 32];
    __shared__ unsigned short B1lds[128 * 32];
    __shared__ unsigned short B2lds[128 * 32];

    const int tid  = threadIdx.x;
    const int wave = tid >> 6, lane = tid & 63;
    const int wr = wave >> 1, wc = wave & 1;
    const int l15 = lane & 15, l4 = lane >> 4;
    const int row0 = blockIdx.y * 64, col0 = blockIdx.x * 128;

    f32x4 acc1[2][4], acc2[2][4];
#pragma unroll
    for (int i = 0; i < 2; ++i)
#pragma unroll
        for (int j = 0; j < 4; ++j) { acc1[i][j] = (f32x4)0.0f; acc2[i][j] = (f32x4)0.0f; }

    int aoff[2], boff[4];
#pragma unroll
    for (int mi = 0; mi < 2; ++mi) aoff[mi] = ((wr * 32 + mi * 16 + l15) * 32 + l4 * 8) * 2;
#pragma unroll
    for (int ni = 0; ni < 4; ++ni) boff[ni] = ((wc * 64 + ni * 16 + l15) * 32 + l4 * 8) * 2;

    for (int k0 = 0; k0 < K; k0 += 32) {
        __syncthreads();
        {   // A: 64x32 = 4KB = one issue
            const int base = wave * 64;
            const int idx  = base + lane;
            const int r = idx >> 2, sg = idx & 3;
            gload_lds16(A + (size_t)(row0 + r) * K + k0 + sg * 8, (char*)Alds + base * 16);
        }
#pragma unroll
        for (int i = 0; i < 2; ++i) {
            const int base = i * 256 + wave * 64;
            const int idx  = base + lane;
            const int r = idx >> 2, sg = idx & 3;
            gload_lds16(Bg + (size_t)(col0 + r) * K + k0 + sg * 8, (char*)B1lds + base * 16);
            gload_lds16(Bu + (size_t)(col0 + r) * K + k0 + sg * 8, (char*)B2lds + base * 16);
        }
        __syncthreads();

        bf16x8 af[2], b1[4], b2[4];
#pragma unroll
        for (int mi = 0; mi < 2; ++mi) af[mi] = *(const bf16x8*)((const char*)Alds + aoff[mi]);
#pragma unroll
        for (int ni = 0; ni < 4; ++ni) {
            b1[ni] = *(const bf16x8*)((const char*)B1lds + boff[ni]);
            b2[ni] = *(const bf16x8*)((const char*)B2lds + boff[ni]);
        }
#pragma unroll
        for (int mi = 0; mi < 2; ++mi)
#pragma unroll
            for (int ni = 0; ni < 4; ++ni) {
                acc1[mi][ni] = __builtin_amdgcn_mfma_f32_16x16x32_bf16(
                    af[mi], b1[ni], acc1[mi][ni], 0, 0, 0);
                acc2[mi][ni] = __builtin_amdgcn_mfma_f32_16x16x32_bf16(
                    af[mi], b2[ni], acc2[mi][ni], 0, 0, 0);
            }
    }

#pragma unroll
    for (int mi = 0; mi < 2; ++mi) {
        const int rowb = row0 + wr * 32 + mi * 16 + l4 * 4;
#pragma unroll
        for (int ni = 0; ni < 4; ++ni) {
            const int col = col0 + wc * 64 + ni * 16 + l15;
#pragma unroll
            for (int r = 0; r < 4; ++r) {
                const float g = gelu_exact(acc1[mi][ni][r]) * acc2[mi][ni][r];
                Cbf[(size_t)(rowb + r) * N + col] = f2b(g);
            }
        }
    }
}

// ---------------------------------------------------------------------------
// Flash-style attention (fp32 math). One block = (b, h, 64-query tile).
// Writes ctx directly as bf16 for the Wo GEMM.
// ---------------------------------------------------------------------------
__global__ __launch_bounds__(256) void attn_kernel(
    const float* __restrict__ qkv, const float* __restrict__ slopes,
    unsigned short* __restrict__ ctx_bf)
{
    __shared__ float Ks[64][68];
    __shared__ float Vs[64][68];
    __shared__ float Ps[64][68];

    const int q0 = blockIdx.x * 64;
    const int h  = blockIdx.y;
    const int b  = blockIdx.z;
    const int tid = threadIdx.x;
    const int qr = tid >> 2;
    const int qc = tid & 3;
    const float slope = slopes[h];
    const float scale = 0.125f;

    float q[HD];
    {
        const float* qrow = qkv + ((size_t)(b * SS + q0 + qr)) * QKV_N + h * HD;
#pragma unroll
        for (int i = 0; i < HD / 4; ++i) {
            float4 t = *(const float4*)&qrow[i * 4];
            q[i*4+0] = t.x; q[i*4+1] = t.y; q[i*4+2] = t.z; q[i*4+3] = t.w;
        }
    }

    float mrun = -1e30f, lrun = 0.f;
    float o[16] = {};

    for (int kt = 0; kt < SS; kt += 64) {
        __syncthreads();
        {
            const float* kbase = qkv + ((size_t)(b * SS + kt + qr)) * QKV_N + DIM + h * HD;
            const float* vbase = kbase + DIM;
#pragma unroll
            for (int i = 0; i < 4; ++i) {
                *(float4*)&Ks[qr][qc * 16 + i * 4] = *(const float4*)&kbase[qc * 16 + i * 4];
                *(float4*)&Vs[qr][qc * 16 + i * 4] = *(const float4*)&vbase[qc * 16 + i * 4];
            }
        }
        __syncthreads();

        float p[16];
        float tmax = -1e30f;
#pragma unroll
        for (int j = 0; j < 16; ++j) {
            const int c = qc * 16 + j;
            float s = 0.f;
#pragma unroll
            for (int d4 = 0; d4 < 16; ++d4) {
                float4 kv = *(const float4*)&Ks[c][d4 * 4];
                s = fmaf(q[d4*4+0], kv.x, s);
                s = fmaf(q[d4*4+1], kv.y, s);
                s = fmaf(q[d4*4+2], kv.z, s);
                s = fmaf(q[d4*4+3], kv.w, s);
            }
            int dist = (q0 + qr) - (kt + c);
            s = s * scale - slope * fabsf((float)dist);
            p[j] = s;
            tmax = fmaxf(tmax, s);
        }
        tmax = fmaxf(tmax, __shfl_xor(tmax, 1));
        tmax = fmaxf(tmax, __shfl_xor(tmax, 2));
        const float mnew = fmaxf(mrun, tmax);
        const float corr = __expf(mrun - mnew);
        float lsum = 0.f;
#pragma unroll
        for (int j = 0; j < 16; ++j) {
            p[j] = __expf(p[j] - mnew);
            lsum += p[j];
        }
        lsum += __shfl_xor(lsum, 1);
        lsum += __shfl_xor(lsum, 2);
        lrun = lrun * corr + lsum;
        mrun = mnew;
#pragma unroll
        for (int j = 0; j < 16; ++j) o[j] *= corr;

#pragma unroll
        for (int j4 = 0; j4 < 4; ++j4) {
            float4 w; w.x = p[j4*4+0]; w.y = p[j4*4+1]; w.z = p[j4*4+2]; w.w = p[j4*4+3];
            *(float4*)&Ps[qr][qc * 16 + j4 * 4] = w;
        }
        __syncthreads();

#pragma unroll 8
        for (int c = 0; c < 64; ++c) {
            const float pc = Ps[qr][c];
#pragma unroll
            for (int j4 = 0; j4 < 4; ++j4) {
                float4 v = *(const float4*)&Vs[c][qc * 16 + j4 * 4];
                o[j4*4+0] = fmaf(pc, v.x, o[j4*4+0]);
                o[j4*4+1] = fmaf(pc, v.y, o[j4*4+1]);
                o[j4*4+2] = fmaf(pc, v.z, o[j4*4+2]);
                o[j4*4+3] = fmaf(pc, v.w, o[j4*4+3]);
            }
        }
    }

    const float inv = 1.0f / lrun;
    unsigned short* crow = ctx_bf + ((size_t)(b * SS + q0 + qr)) * DIM + h * HD + qc * 16;
#pragma unroll
    for (int j4 = 0; j4 < 4; ++j4) {
        ushort4 w;
        w.x = f2b(o[j4*4+0] * inv); w.y = f2b(o[j4*4+1] * inv);
        w.z = f2b(o[j4*4+2] * inv); w.w = f2b(o[j4*4+3] * inv);
        ((ushort4*)crow)[j4] = w;
    }
}

// ---------------------------------------------------------------------------
// LayerNorm (two-pass variance). In-place safe (reads precede writes).
// Optionally emits a bf16 copy for the next GEMM's A operand.
// ---------------------------------------------------------------------------
__global__ __launch_bounds__(256) void ln_kernel(
    const float* __restrict__ x, const float* __restrict__ gw,
    const float* __restrict__ bw, float* __restrict__ y,
    unsigned short* __restrict__ ybf)
{
    const int row = blockIdx.x;
    const int tid = threadIdx.x;
    const float* xr = x + (size_t)row * DIM;
    float v0 = xr[tid], v1 = xr[tid + 256], v2 = xr[tid + 512];

    __shared__ float red[8];
    float s = v0 + v1 + v2;
#pragma unroll
    for (int off = 1; off < 64; off <<= 1) s += __shfl_xor(s, off);
    const int wid = tid >> 6;
    if ((tid & 63) == 0) red[wid] = s;
    __syncthreads();
    const float mean = (red[0] + red[1] + red[2] + red[3]) * (1.0f / DIM);

    const float d0 = v0 - mean, d1 = v1 - mean, d2 = v2 - mean;
    float ss = d0 * d0 + d1 * d1 + d2 * d2;
#pragma unroll
    for (int off = 1; off < 64; off <<= 1) ss += __shfl_xor(ss, off);
    if ((tid & 63) == 0) red[4 + wid] = ss;
    __syncthreads();
    const float var = (red[4] + red[5] + red[6] + red[7]) * (1.0f / DIM);
    const float r = rsqrtf(fmaxf(var, 0.0f) + 1e-12f);

    const float o0 = d0 * r * gw[tid]       + bw[tid];
    const float o1 = d1 * r * gw[tid + 256] + bw[tid + 256];
    const float o2 = d2 * r * gw[tid + 512] + bw[tid + 512];
    float* yr = y + (size_t)row * DIM;
    yr[tid] = o0; yr[tid + 256] = o1; yr[tid + 512] = o2;
    if (ybf) {
        unsigned short* br = ybf + (size_t)row * DIM;
        br[tid] = f2b(o0); br[tid + 256] = f2b(o1); br[tid + 512] = f2b(o2);
    }
}

// ---------------------------------------------------------------------------
extern "C" void kernel_launch(void* const* d_in, const int* in_sizes, int n_in,
                              void* d_out, int out_size, void* d_ws, size_t ws_size,
                              hipStream_t stream)
{
    const float* x      = (const float*)d_in[0];
    const float* slopes = (const float*)d_in[4];
    const float* Wqkv   = (const float*)d_in[5];
    const float* bqkv   = (const float*)d_in[6];
    const float* Wo     = (const float*)d_in[7];
    const float* bo     = (const float*)d_in[8];
    const float* ln1g   = (const float*)d_in[9];
    const float* ln1b   = (const float*)d_in[10];
    const float* Wglu   = (const float*)d_in[11];
    const float* Wdown  = (const float*)d_in[12];
    const float* bdown  = (const float*)d_in[13];
    const float* ln2g   = (const float*)d_in[14];
    const float* ln2b   = (const float*)d_in[15];
    float* out = (float*)d_out;
    char*  w   = (char*)d_ws;

    // ---- workspace layout (bytes) ----
    // W area (persistent bf16 weights): 18,874,368
    unsigned short* Wqkv_bf  = (unsigned short*)(w);                 // 3,538,944
    unsigned short* Wo_bf    = (unsigned short*)(w + 3538944);       // 1,179,648
    unsigned short* Wglu_bf  = (unsigned short*)(w + 4718592);       // 9,437,184
    unsigned short* Wdown_bf = (unsigned short*)(w + 14155776);      // 4,718,592
    char* R = w + 18874368;                                          // aliased region, 88,080,384
    unsigned short* x_bf     = (unsigned short*)(R);                 // [0, 12.6M)   until qkv gemm
    float*          qkv      = (float*)(R + 12582912);               // [12.6M, 88.1M) until attn
    unsigned short* ctx_bf   = (unsigned short*)(R);                 // [0, 12.6M)   attn..wo (x_bf dead)
    unsigned short* ao_bf    = (unsigned short*)(R + 12582912);      // [12.6M, 25.2M) ln1..glu (qkv dead)
    unsigned short* gated_bf = (unsigned short*)(R + 25165824);      // [25.2M, 75.5M) glu..down
    float* D = (float*)(w + 18874368 + 88080384);                    // 25,165,824 (attn_out/resid, in-place LN)
    // total: 132,120,576 bytes

    // ---- bf16 conversions ----
    {
        int n4;
        n4 = NROWS * DIM / 4;
        cvt_bf16_kernel<<<(n4 + 255) / 256, 256, 0, stream>>>(x, x_bf, n4);
        n4 = QKV_N * DIM / 4;
        cvt_bf16_kernel<<<(n4 + 255) / 256, 256, 0, stream>>>(Wqkv, Wqkv_bf, n4);
        n4 = DIM * DIM / 4;
        cvt_bf16_kernel<<<(n4 + 255) / 256, 256, 0, stream>>>(Wo, Wo_bf, n4);
        n4 = 2 * II * DIM / 4;
        cvt_bf16_kernel<<<(n4 + 255) / 256, 256, 0, stream>>>(Wglu, Wglu_bf, n4);
        n4 = DIM * II / 4;
        cvt_bf16_kernel<<<(n4 + 255) / 256, 256, 0, stream>>>(Wdown, Wdown_bf, n4);
    }

    // 1) qkv = x @ Wqkv^T + bqkv
    gemm_bf16_f32<<<dim3(QKV_N / 128, NROWS / 128), 256, 0, stream>>>(
        x_bf, Wqkv_bf, bqkv, nullptr, qkv, NROWS, QKV_N, DIM);

    // 2) attention -> ctx (bf16)
    attn_kernel<<<dim3(SS / 64, HH, BB), 256, 0, stream>>>(qkv, slopes, ctx_bf);

    // 3) D = ctx @ Wo^T + bo + x
    gemm_bf16_f32<<<dim3(DIM / 128, NROWS / 128), 256, 0, stream>>>(
        ctx_bf, Wo_bf, bo, x, D, NROWS, DIM, DIM);

    // 4) D = LN1(D) (in-place) ; ao_bf = bf16(D)
    ln_kernel<<<NROWS, 256, 0, stream>>>(D, ln1g, ln1b, D, ao_bf);

    // 5) gated = gelu(ao @ Wglu_g^T) * (ao @ Wglu_u^T)  (bf16 out)
    gemm_bf16_glu<<<dim3(II / 128, NROWS / 64), 256, 0, stream>>>(
        ao_bf, Wglu_bf, Wglu_bf + (size_t)II * DIM, gated_bf, NROWS, II, DIM);

    // 6) D = gated @ Wdown^T + bdown + D   (in-place residual)
    gemm_bf16_f32<<<dim3(DIM / 128, NROWS / 128), 256, 0, stream>>>(
        gated_bf, Wdown_bf, bdown, D, D, NROWS, DIM, II);

    // 7) out = LN2(D)
    ln_kernel<<<NROWS, 256, 0, stream>>>(D, ln2g, ln2b, out, nullptr);
}

// Round 7
// 727.162 us; speedup vs baseline: 3.8050x; 1.5212x over previous
//
#include <hip/hip_runtime.h>
#include <hip/hip_bf16.h>
#include <math.h>

// Problem constants
#define BB 16
#define SS 512
#define DIM 768
#define HH 12
#define HD 64
#define II 3072
#define NROWS (BB*SS)          // 8192
#define QKV_N (3*DIM)          // 2304

typedef __attribute__((ext_vector_type(8))) short bf16x8;
typedef __attribute__((ext_vector_type(4))) float f32x4;

__device__ __forceinline__ unsigned short f2b(float f) {
    __hip_bfloat16 h = __float2bfloat16(f);   // RNE
    return *reinterpret_cast<unsigned short*>(&h);
}

__device__ __forceinline__ void gload_lds16(const void* g, void* l) {
    // wave-uniform LDS base; HW scatters lane*16
    __builtin_amdgcn_global_load_lds(
        (const __attribute__((address_space(1))) void*)g,
        (__attribute__((address_space(3))) void*)l, 16, 0, 0);
}

__device__ __forceinline__ float gelu_exact(float x) {
    return 0.5f * x * (1.0f + erff(x * 0.70710678118654752f));
}

// ---------------------------------------------------------------------------
// fp32 -> bf16 conversion (vectorized, grid-stride). n4 = n/4.
// ---------------------------------------------------------------------------
__global__ __launch_bounds__(256) void cvt_bf16_kernel(
    const float* __restrict__ src, unsigned short* __restrict__ dst, int n4)
{
    const int stride = gridDim.x * 256;
    for (int i = blockIdx.x * 256 + threadIdx.x; i < n4; i += stride) {
        float4 v = ((const float4*)src)[i];
        ushort4 o;
        o.x = f2b(v.x); o.y = f2b(v.y); o.z = f2b(v.z); o.w = f2b(v.w);
        ((ushort4*)dst)[i] = o;
    }
}

// ---------------------------------------------------------------------------
// bf16 MFMA GEMM, NT: C[m,n] = sum_k A[m,k]*B[n,k] + bias[n] (+resid[m,n])
// A,B bf16 row-major (ld = K). C fp32. 128x128 tile, BK=32, 4 waves (2x2).
// ---------------------------------------------------------------------------
__global__ __launch_bounds__(256) void gemm_bf16_f32(
    const unsigned short* __restrict__ A, const unsigned short* __restrict__ B,
    const float* __restrict__ bias, const float* __restrict__ resid,
    float* __restrict__ C, int M, int N, int K)
{
    __shared__ unsigned short Alds[128 * 32];
    __shared__ unsigned short Blds[128 * 32];

    const int tid  = threadIdx.x;
    const int wave = tid >> 6, lane = tid & 63;
    const int wr = wave >> 1, wc = wave & 1;
    const int l15 = lane & 15, l4 = lane >> 4;
    const int row0 = blockIdx.y * 128, col0 = blockIdx.x * 128;

    f32x4 acc[4][4];
#pragma unroll
    for (int i = 0; i < 4; ++i)
#pragma unroll
        for (int j = 0; j < 4; ++j) acc[i][j] = (f32x4)0.0f;

    int aoff[4], boff[4];
#pragma unroll
    for (int mi = 0; mi < 4; ++mi) aoff[mi] = ((wr * 64 + mi * 16 + l15) * 32 + l4 * 8) * 2;
#pragma unroll
    for (int ni = 0; ni < 4; ++ni) boff[ni] = ((wc * 64 + ni * 16 + l15) * 32 + l4 * 8) * 2;

    for (int k0 = 0; k0 < K; k0 += 32) {
        __syncthreads();
#pragma unroll
        for (int i = 0; i < 2; ++i) {
            const int base = i * 256 + wave * 64;   // wave-uniform
            const int idx  = base + lane;
            const int r = idx >> 2, sg = idx & 3;
            gload_lds16(A + (size_t)(row0 + r) * K + k0 + sg * 8, (char*)Alds + base * 16);
            gload_lds16(B + (size_t)(col0 + r) * K + k0 + sg * 8, (char*)Blds + base * 16);
        }
        __syncthreads();

        bf16x8 af[4], bfr[4];
#pragma unroll
        for (int mi = 0; mi < 4; ++mi) af[mi]  = *(const bf16x8*)((const char*)Alds + aoff[mi]);
#pragma unroll
        for (int ni = 0; ni < 4; ++ni) bfr[ni] = *(const bf16x8*)((const char*)Blds + boff[ni]);
#pragma unroll
        for (int mi = 0; mi < 4; ++mi)
#pragma unroll
            for (int ni = 0; ni < 4; ++ni)
                acc[mi][ni] = __builtin_amdgcn_mfma_f32_16x16x32_bf16(
                    af[mi], bfr[ni], acc[mi][ni], 0, 0, 0);
    }

    float bv[4];
#pragma unroll
    for (int ni = 0; ni < 4; ++ni) bv[ni] = bias[col0 + wc * 64 + ni * 16 + l15];

#pragma unroll
    for (int mi = 0; mi < 4; ++mi) {
        const int rowb = row0 + wr * 64 + mi * 16 + l4 * 4;
#pragma unroll
        for (int ni = 0; ni < 4; ++ni) {
            const int col = col0 + wc * 64 + ni * 16 + l15;
#pragma unroll
            for (int r = 0; r < 4; ++r) {
                float v = acc[mi][ni][r] + bv[ni];
                const size_t off = (size_t)(rowb + r) * N + col;
                if (resid) v += resid[off];
                C[off] = v;
            }
        }
    }
}

// ---------------------------------------------------------------------------
// QKV GEMM: same main loop, epilogue scatters to bf16 Q[b,h,s,d] (x0.125),
// K[b,h,s,d], V^T[b,h,d,s]. Tile is purely Q, K, or V (768 % 128 == 0).
// ---------------------------------------------------------------------------
__global__ __launch_bounds__(256) void gemm_qkv(
    const unsigned short* __restrict__ A, const unsigned short* __restrict__ B,
    const float* __restrict__ bias,
    unsigned short* __restrict__ Qo, unsigned short* __restrict__ Ko,
    unsigned short* __restrict__ Vo, int M, int N, int K)
{
    __shared__ unsigned short Alds[128 * 32];
    __shared__ unsigned short Blds[128 * 32];

    const int tid  = threadIdx.x;
    const int wave = tid >> 6, lane = tid & 63;
    const int wr = wave >> 1, wc = wave & 1;
    const int l15 = lane & 15, l4 = lane >> 4;
    const int row0 = blockIdx.y * 128, col0 = blockIdx.x * 128;

    f32x4 acc[4][4];
#pragma unroll
    for (int i = 0; i < 4; ++i)
#pragma unroll
        for (int j = 0; j < 4; ++j) acc[i][j] = (f32x4)0.0f;

    int aoff[4], boff[4];
#pragma unroll
    for (int mi = 0; mi < 4; ++mi) aoff[mi] = ((wr * 64 + mi * 16 + l15) * 32 + l4 * 8) * 2;
#pragma unroll
    for (int ni = 0; ni < 4; ++ni) boff[ni] = ((wc * 64 + ni * 16 + l15) * 32 + l4 * 8) * 2;

    for (int k0 = 0; k0 < K; k0 += 32) {
        __syncthreads();
#pragma unroll
        for (int i = 0; i < 2; ++i) {
            const int base = i * 256 + wave * 64;
            const int idx  = base + lane;
            const int r = idx >> 2, sg = idx & 3;
            gload_lds16(A + (size_t)(row0 + r) * K + k0 + sg * 8, (char*)Alds + base * 16);
            gload_lds16(B + (size_t)(col0 + r) * K + k0 + sg * 8, (char*)Blds + base * 16);
        }
        __syncthreads();

        bf16x8 af[4], bfr[4];
#pragma unroll
        for (int mi = 0; mi < 4; ++mi) af[mi]  = *(const bf16x8*)((const char*)Alds + aoff[mi]);
#pragma unroll
        for (int ni = 0; ni < 4; ++ni) bfr[ni] = *(const bf16x8*)((const char*)Blds + boff[ni]);
#pragma unroll
        for (int mi = 0; mi < 4; ++mi)
#pragma unroll
            for (int ni = 0; ni < 4; ++ni)
                acc[mi][ni] = __builtin_amdgcn_mfma_f32_16x16x32_bf16(
                    af[mi], bfr[ni], acc[mi][ni], 0, 0, 0);
    }

    const int region = col0 / DIM;      // 0=Q, 1=K, 2=V (block-uniform)
    float bv[4];
#pragma unroll
    for (int ni = 0; ni < 4; ++ni) bv[ni] = bias[col0 + wc * 64 + ni * 16 + l15];

#pragma unroll
    for (int mi = 0; mi < 4; ++mi) {
        const int rowb = row0 + wr * 64 + mi * 16 + l4 * 4;
        const int bidx = rowb >> 9;         // / 512
        const int s0   = rowb & 511;
#pragma unroll
        for (int ni = 0; ni < 4; ++ni) {
            const int n  = col0 + wc * 64 + ni * 16 + l15;
            const int nn = n - region * DIM;
            const int hh = nn >> 6, d = nn & 63;
            if (region == 2) {
                ushort4 w;
                w.x = f2b(acc[mi][ni][0] + bv[ni]);
                w.y = f2b(acc[mi][ni][1] + bv[ni]);
                w.z = f2b(acc[mi][ni][2] + bv[ni]);
                w.w = f2b(acc[mi][ni][3] + bv[ni]);
                *(ushort4*)&Vo[(((size_t)bidx * HH + hh) * HD + d) * SS + s0] = w;
            } else {
                unsigned short* dst = region ? Ko : Qo;
                const float scl = region ? 1.0f : 0.125f;   // fold 1/sqrt(HD) into Q
#pragma unroll
                for (int r = 0; r < 4; ++r)
                    dst[(((size_t)bidx * HH + hh) * SS + s0 + r) * HD + d] =
                        f2b((acc[mi][ni][r] + bv[ni]) * scl);
            }
        }
    }
}

// ---------------------------------------------------------------------------
// GLU GEMM: gated[m,n] = gelu(A @ Bg[n]^T) * (A @ Bu[n]^T), bf16 out.
// ---------------------------------------------------------------------------
__global__ __launch_bounds__(256) void gemm_bf16_glu(
    const unsigned short* __restrict__ A, const unsigned short* __restrict__ Bg,
    const unsigned short* __restrict__ Bu, unsigned short* __restrict__ Cbf,
    int M, int N, int K)
{
    __shared__ unsigned short Alds[64 * 32];
    __shared__ unsigned short B1lds[128 * 32];
    __shared__ unsigned short B2lds[128 * 32];

    const int tid  = threadIdx.x;
    const int wave = tid >> 6, lane = tid & 63;
    const int wr = wave >> 1, wc = wave & 1;
    const int l15 = lane & 15, l4 = lane >> 4;
    const int row0 = blockIdx.y * 64, col0 = blockIdx.x * 128;

    f32x4 acc1[2][4], acc2[2][4];
#pragma unroll
    for (int i = 0; i < 2; ++i)
#pragma unroll
        for (int j = 0; j < 4; ++j) { acc1[i][j] = (f32x4)0.0f; acc2[i][j] = (f32x4)0.0f; }

    int aoff[2], boff[4];
#pragma unroll
    for (int mi = 0; mi < 2; ++mi) aoff[mi] = ((wr * 32 + mi * 16 + l15) * 32 + l4 * 8) * 2;
#pragma unroll
    for (int ni = 0; ni < 4; ++ni) boff[ni] = ((wc * 64 + ni * 16 + l15) * 32 + l4 * 8) * 2;

    for (int k0 = 0; k0 < K; k0 += 32) {
        __syncthreads();
        {
            const int base = wave * 64;
            const int idx  = base + lane;
            const int r = idx >> 2, sg = idx & 3;
            gload_lds16(A + (size_t)(row0 + r) * K + k0 + sg * 8, (char*)Alds + base * 16);
        }
#pragma unroll
        for (int i = 0; i < 2; ++i) {
            const int base = i * 256 + wave * 64;
            const int idx  = base + lane;
            const int r = idx >> 2, sg = idx & 3;
            gload_lds16(Bg + (size_t)(col0 + r) * K + k0 + sg * 8, (char*)B1lds + base * 16);
            gload_lds16(Bu + (size_t)(col0 + r) * K + k0 + sg * 8, (char*)B2lds + base * 16);
        }
        __syncthreads();

        bf16x8 af[2], b1[4], b2[4];
#pragma unroll
        for (int mi = 0; mi < 2; ++mi) af[mi] = *(const bf16x8*)((const char*)Alds + aoff[mi]);
#pragma unroll
        for (int ni = 0; ni < 4; ++ni) {
            b1[ni] = *(const bf16x8*)((const char*)B1lds + boff[ni]);
            b2[ni] = *(const bf16x8*)((const char*)B2lds + boff[ni]);
        }
#pragma unroll
        for (int mi = 0; mi < 2; ++mi)
#pragma unroll
            for (int ni = 0; ni < 4; ++ni) {
                acc1[mi][ni] = __builtin_amdgcn_mfma_f32_16x16x32_bf16(
                    af[mi], b1[ni], acc1[mi][ni], 0, 0, 0);
                acc2[mi][ni] = __builtin_amdgcn_mfma_f32_16x16x32_bf16(
                    af[mi], b2[ni], acc2[mi][ni], 0, 0, 0);
            }
    }

#pragma unroll
    for (int mi = 0; mi < 2; ++mi) {
        const int rowb = row0 + wr * 32 + mi * 16 + l4 * 4;
#pragma unroll
        for (int ni = 0; ni < 4; ++ni) {
            const int col = col0 + wc * 64 + ni * 16 + l15;
#pragma unroll
            for (int r = 0; r < 4; ++r) {
                const float g = gelu_exact(acc1[mi][ni][r]) * acc2[mi][ni][r];
                Cbf[(size_t)(rowb + r) * N + col] = f2b(g);
            }
        }
    }
}

// ---------------------------------------------------------------------------
// MFMA flash attention. Block = (b, h, 64 q-rows); 4 waves x 16 q-rows each.
// Q pre-scaled by 0.125. Q/K row-major [b,h,s,d]; V transposed [b,h,d,s].
// Frag loads direct from global (K/V are L1/L2-resident). Only LDS use:
// wave-private 16x72 P transpose tile (C-frag -> A-frag redistribution).
// ---------------------------------------------------------------------------
__global__ __launch_bounds__(256) void attn_mfma(
    const unsigned short* __restrict__ Q, const unsigned short* __restrict__ K,
    const unsigned short* __restrict__ V, const float* __restrict__ slopes,
    unsigned short* __restrict__ ctx)
{
    __shared__ unsigned short Ps[4][16][72];   // pitch 72: 144B rows, 16B-aligned

    const int tid = threadIdx.x, wave = tid >> 6, lane = tid & 63;
    const int l15 = lane & 15, l4 = lane >> 4;
    const int q0 = blockIdx.x * 64, h = blockIdx.y, b = blockIdx.z;
    const int bh = b * HH + h;
    const float slope = slopes[h];

    const unsigned short* Qb = Q + (size_t)bh * SS * HD;
    const unsigned short* Kb = K + (size_t)bh * SS * HD;
    const unsigned short* Vb = V + (size_t)bh * HD * SS;

    const int qrow = q0 + wave * 16 + l15;     // A-frag row (m = l&15)
    bf16x8 qa0 = *(const bf16x8*)(Qb + (size_t)qrow * HD + l4 * 8);
    bf16x8 qa1 = *(const bf16x8*)(Qb + (size_t)qrow * HD + 32 + l4 * 8);

    float mrun[4], lrun[4];
    f32x4 oacc[4];
#pragma unroll
    for (int r = 0; r < 4; ++r) { mrun[r] = -1e30f; lrun[r] = 0.f; }
#pragma unroll
    for (int df = 0; df < 4; ++df) oacc[df] = (f32x4)0.f;

    const float ibase = (float)(q0 + wave * 16 + l4 * 4);   // C-frag row base

    for (int kt = 0; kt < SS; kt += 64) {
        // ---- QK^T: S[16 x 64] ----
        f32x4 sc[4];
#pragma unroll
        for (int nf = 0; nf < 4; ++nf) {
            const unsigned short* kr = Kb + (size_t)(kt + nf * 16 + l15) * HD + l4 * 8;
            f32x4 z = (f32x4)0.f;
            z = __builtin_amdgcn_mfma_f32_16x16x32_bf16(qa0, *(const bf16x8*)kr, z, 0, 0, 0);
            z = __builtin_amdgcn_mfma_f32_16x16x32_bf16(qa1, *(const bf16x8*)(kr + 32), z, 0, 0, 0);
            sc[nf] = z;
        }
        // ---- ALiBi + online softmax (C-frag: col=l15 -> j, row=l4*4+r -> i) ----
        float sv[4][4], mx[4];
#pragma unroll
        for (int r = 0; r < 4; ++r) mx[r] = -1e30f;
#pragma unroll
        for (int nf = 0; nf < 4; ++nf) {
            const float jf = (float)(kt + nf * 16 + l15);
#pragma unroll
            for (int r = 0; r < 4; ++r) {
                const float s = sc[nf][r] - slope * fabsf(ibase + (float)r - jf);
                sv[nf][r] = s;
                mx[r] = fmaxf(mx[r], s);
            }
        }
#pragma unroll
        for (int r = 0; r < 4; ++r) {
            mx[r] = fmaxf(mx[r], __shfl_xor(mx[r], 1));
            mx[r] = fmaxf(mx[r], __shfl_xor(mx[r], 2));
            mx[r] = fmaxf(mx[r], __shfl_xor(mx[r], 4));
            mx[r] = fmaxf(mx[r], __shfl_xor(mx[r], 8));
        }
        float corr[4], lsum[4];
#pragma unroll
        for (int r = 0; r < 4; ++r) {
            const float mnew = fmaxf(mrun[r], mx[r]);
            corr[r] = __expf(mrun[r] - mnew);
            mrun[r] = mnew;
            lsum[r] = 0.f;
        }
#pragma unroll
        for (int nf = 0; nf < 4; ++nf)
#pragma unroll
            for (int r = 0; r < 4; ++r) {
                const float e = __expf(sv[nf][r] - mrun[r]);
                sv[nf][r] = e;
                lsum[r] += e;
            }
#pragma unroll
        for (int r = 0; r < 4; ++r) {
            lsum[r] += __shfl_xor(lsum[r], 1);
            lsum[r] += __shfl_xor(lsum[r], 2);
            lsum[r] += __shfl_xor(lsum[r], 4);
            lsum[r] += __shfl_xor(lsum[r], 8);
            lrun[r] = lrun[r] * corr[r] + lsum[r];
        }
#pragma unroll
        for (int df = 0; df < 4; ++df)
#pragma unroll
            for (int r = 0; r < 4; ++r) oacc[df][r] *= corr[r];

        // ---- P: C-frag -> bf16 A-frag via wave-private LDS ----
#pragma unroll
        for (int nf = 0; nf < 4; ++nf)
#pragma unroll
            for (int r = 0; r < 4; ++r)
                Ps[wave][l4 * 4 + r][nf * 16 + l15] = f2b(sv[nf][r]);
        const bf16x8 pa0 = *(const bf16x8*)&Ps[wave][l15][l4 * 8];
        const bf16x8 pa1 = *(const bf16x8*)&Ps[wave][l15][32 + l4 * 8];

        // ---- PV: O[16 x 64] += P @ V ----
#pragma unroll
        for (int df = 0; df < 4; ++df) {
            const unsigned short* vr = Vb + (size_t)(df * 16 + l15) * SS + kt + l4 * 8;
            oacc[df] = __builtin_amdgcn_mfma_f32_16x16x32_bf16(pa0, *(const bf16x8*)vr, oacc[df], 0, 0, 0);
            oacc[df] = __builtin_amdgcn_mfma_f32_16x16x32_bf16(pa1, *(const bf16x8*)(vr + 32), oacc[df], 0, 0, 0);
        }
    }

    float inv[4];
#pragma unroll
    for (int r = 0; r < 4; ++r) inv[r] = 1.0f / lrun[r];
    unsigned short* cb = ctx + ((size_t)(b * SS + q0 + wave * 16 + l4 * 4)) * DIM + h * HD + l15;
#pragma unroll
    for (int df = 0; df < 4; ++df)
#pragma unroll
        for (int r = 0; r < 4; ++r)
            cb[(size_t)r * DIM + df * 16] = f2b(oacc[df][r] * inv[r]);
}

// ---------------------------------------------------------------------------
// LayerNorm (two-pass variance). In-place safe. Optional bf16 copy out.
// ---------------------------------------------------------------------------
__global__ __launch_bounds__(256) void ln_kernel(
    const float* __restrict__ x, const float* __restrict__ gw,
    const float* __restrict__ bw, float* __restrict__ y,
    unsigned short* __restrict__ ybf)
{
    const int row = blockIdx.x;
    const int tid = threadIdx.x;
    const float* xr = x + (size_t)row * DIM;
    float v0 = xr[tid], v1 = xr[tid + 256], v2 = xr[tid + 512];

    __shared__ float red[8];
    float s = v0 + v1 + v2;
#pragma unroll
    for (int off = 1; off < 64; off <<= 1) s += __shfl_xor(s, off);
    const int wid = tid >> 6;
    if ((tid & 63) == 0) red[wid] = s;
    __syncthreads();
    const float mean = (red[0] + red[1] + red[2] + red[3]) * (1.0f / DIM);

    const float d0 = v0 - mean, d1 = v1 - mean, d2 = v2 - mean;
    float ss = d0 * d0 + d1 * d1 + d2 * d2;
#pragma unroll
    for (int off = 1; off < 64; off <<= 1) ss += __shfl_xor(ss, off);
    if ((tid & 63) == 0) red[4 + wid] = ss;
    __syncthreads();
    const float var = (red[4] + red[5] + red[6] + red[7]) * (1.0f / DIM);
    const float r = rsqrtf(fmaxf(var, 0.0f) + 1e-12f);

    const float o0 = d0 * r * gw[tid]       + bw[tid];
    const float o1 = d1 * r * gw[tid + 256] + bw[tid + 256];
    const float o2 = d2 * r * gw[tid + 512] + bw[tid + 512];
    float* yr = y + (size_t)row * DIM;
    yr[tid] = o0; yr[tid + 256] = o1; yr[tid + 512] = o2;
    if (ybf) {
        unsigned short* br = ybf + (size_t)row * DIM;
        br[tid] = f2b(o0); br[tid + 256] = f2b(o1); br[tid + 512] = f2b(o2);
    }
}

// ---------------------------------------------------------------------------
extern "C" void kernel_launch(void* const* d_in, const int* in_sizes, int n_in,
                              void* d_out, int out_size, void* d_ws, size_t ws_size,
                              hipStream_t stream)
{
    const float* x      = (const float*)d_in[0];
    const float* slopes = (const float*)d_in[4];
    const float* Wqkv   = (const float*)d_in[5];
    const float* bqkv   = (const float*)d_in[6];
    const float* Wo     = (const float*)d_in[7];
    const float* bo     = (const float*)d_in[8];
    const float* ln1g   = (const float*)d_in[9];
    const float* ln1b   = (const float*)d_in[10];
    const float* Wglu   = (const float*)d_in[11];
    const float* Wdown  = (const float*)d_in[12];
    const float* bdown  = (const float*)d_in[13];
    const float* ln2g   = (const float*)d_in[14];
    const float* ln2b   = (const float*)d_in[15];
    float* out = (float*)d_out;
    char*  w   = (char*)d_ws;

    // ---- workspace layout (bytes), total 119,537,664 ----
    unsigned short* Wqkv_bf  = (unsigned short*)(w);                 // 3,538,944
    unsigned short* Wo_bf    = (unsigned short*)(w + 3538944);       // 1,179,648
    unsigned short* Wglu_bf  = (unsigned short*)(w + 4718592);       // 9,437,184
    unsigned short* Wdown_bf = (unsigned short*)(w + 14155776);      // 4,718,592
    char* R1 = w + 18874368;                                         // 12,582,912
    unsigned short* x_bf     = (unsigned short*)R1;                  // until qkv gemm
    unsigned short* ctx_bf   = (unsigned short*)R1;                  // attn..wo (x_bf dead)
    char* R2 = w + 31457280;                                         // 62,914,560
    unsigned short* Q_bf     = (unsigned short*)(R2);                // 12,582,912 (until attn)
    unsigned short* K_bf     = (unsigned short*)(R2 + 12582912);     // 12,582,912 (until attn)
    unsigned short* V_bf     = (unsigned short*)(R2 + 25165824);     // 12,582,912 (until attn)
    unsigned short* ao_bf    = (unsigned short*)(R2);                // ln1..glu (Q dead)
    unsigned short* gated_bf = (unsigned short*)(R2 + 12582912);     // 50,331,648 (K,V dead)
    float* D = (float*)(w + 94371840);                               // 25,165,824

    // ---- bf16 conversions ----
    {
        int n4;
        n4 = NROWS * DIM / 4;
        cvt_bf16_kernel<<<(n4 + 255) / 256, 256, 0, stream>>>(x, x_bf, n4);
        n4 = QKV_N * DIM / 4;
        cvt_bf16_kernel<<<(n4 + 255) / 256, 256, 0, stream>>>(Wqkv, Wqkv_bf, n4);
        n4 = DIM * DIM / 4;
        cvt_bf16_kernel<<<(n4 + 255) / 256, 256, 0, stream>>>(Wo, Wo_bf, n4);
        n4 = 2 * II * DIM / 4;
        cvt_bf16_kernel<<<(n4 + 255) / 256, 256, 0, stream>>>(Wglu, Wglu_bf, n4);
        n4 = DIM * II / 4;
        cvt_bf16_kernel<<<(n4 + 255) / 256, 256, 0, stream>>>(Wdown, Wdown_bf, n4);
    }

    // 1) QKV GEMM -> scattered bf16 Q (x0.125), K, V^T
    gemm_qkv<<<dim3(QKV_N / 128, NROWS / 128), 256, 0, stream>>>(
        x_bf, Wqkv_bf, bqkv, Q_bf, K_bf, V_bf, NROWS, QKV_N, DIM);

    // 2) MFMA flash attention -> ctx (bf16)
    attn_mfma<<<dim3(SS / 64, HH, BB), 256, 0, stream>>>(
        Q_bf, K_bf, V_bf, slopes, ctx_bf);

    // 3) D = ctx @ Wo^T + bo + x
    gemm_bf16_f32<<<dim3(DIM / 128, NROWS / 128), 256, 0, stream>>>(
        ctx_bf, Wo_bf, bo, x, D, NROWS, DIM, DIM);

    // 4) D = LN1(D) in-place ; ao_bf = bf16(D)
    ln_kernel<<<NROWS, 256, 0, stream>>>(D, ln1g, ln1b, D, ao_bf);

    // 5) gated = gelu(ao @ Wglu_g^T) * (ao @ Wglu_u^T)  (bf16)
    gemm_bf16_glu<<<dim3(II / 128, NROWS / 64), 256, 0, stream>>>(
        ao_bf, Wglu_bf, Wglu_bf + (size_t)II * DIM, gated_bf, NROWS, II, DIM);

    // 6) D = gated @ Wdown^T + bdown + D   (in-place residual)
    gemm_bf16_f32<<<dim3(DIM / 128, NROWS / 128), 256, 0, stream>>>(
        gated_bf, Wdown_bf, bdown, D, D, NROWS, DIM, II);

    // 7) out = LN2(D)
    ln_kernel<<<NROWS, 256, 0, stream>>>(D, ln2g, ln2b, out, nullptr);
}